// Round 1
// baseline (222.588 us; speedup 1.0000x reference)
//
#include <hip/hip_runtime.h>
#include <cmath>

#define N_NODES 200
#define DIM     320
#define GAT_ALPHA 0.2f
#define NEG_INF_V (-9.0e15f)

// ---------------------------------------------------------------------------
// K1: h1 = x @ [W1_0 | W1_1]   (51200 x 320) @ (320 x 64) -> (51200 x 64)
// 64x64 output tile per block, 4x4 register tile per thread, KT=32.
// ---------------------------------------------------------------------------
__global__ __launch_bounds__(256) void gemm_h1(const float* __restrict__ x,
                                               const float* __restrict__ W10,
                                               const float* __restrict__ W11,
                                               float* __restrict__ h1)
{
    __shared__ float xT[32][68];   // [k][row], pad 68 -> 16B aligned rows
    __shared__ float Wl[32][64];   // [k][col]
    const int tid = threadIdx.x;
    const int tr = tid >> 4, tc = tid & 15;
    const int R0 = blockIdx.x * 64;
    float acc[4][4] = {{0.f,0.f,0.f,0.f},{0.f,0.f,0.f,0.f},
                       {0.f,0.f,0.f,0.f},{0.f,0.f,0.f,0.f}};
    for (int k0 = 0; k0 < DIM; k0 += 32) {
        // stage W tile (32 x 64): cols 0..31 from W10, 32..63 from W11
        #pragma unroll
        for (int i = 0; i < 8; ++i) {
            int idx = tid + 256 * i;
            int kk = idx >> 6, c = idx & 63;
            const float* wp = (c < 32) ? (W10 + (k0 + kk) * 32 + c)
                                       : (W11 + (k0 + kk) * 32 + (c - 32));
            Wl[kk][c] = *wp;
        }
        // stage x tile (64 rows x 32 k) transposed into xT[k][row]
        #pragma unroll
        for (int i = 0; i < 2; ++i) {
            int idx4 = tid + 256 * i;
            int row = idx4 >> 3, k4 = (idx4 & 7) << 2;
            const float4 v = *(const float4*)(x + (size_t)(R0 + row) * DIM + k0 + k4);
            xT[k4 + 0][row] = v.x; xT[k4 + 1][row] = v.y;
            xT[k4 + 2][row] = v.z; xT[k4 + 3][row] = v.w;
        }
        __syncthreads();
        #pragma unroll 8
        for (int k = 0; k < 32; ++k) {
            const float4 xv = *(const float4*)(&xT[k][tr << 2]);
            const float4 wv = *(const float4*)(&Wl[k][tc << 2]);
            const float xa[4] = {xv.x, xv.y, xv.z, xv.w};
            const float wa[4] = {wv.x, wv.y, wv.z, wv.w};
            #pragma unroll
            for (int i2 = 0; i2 < 4; ++i2)
                #pragma unroll
                for (int j2 = 0; j2 < 4; ++j2)
                    acc[i2][j2] += xa[i2] * wa[j2];
        }
        __syncthreads();
    }
    #pragma unroll
    for (int i2 = 0; i2 < 4; ++i2) {
        float4 o;
        o.x = acc[i2][0]; o.y = acc[i2][1]; o.z = acc[i2][2]; o.w = acc[i2][3];
        *(float4*)(h1 + (size_t)(R0 + tr * 4 + i2) * 64 + tc * 4) = o;
    }
}

// ---------------------------------------------------------------------------
// K3: h2 = x1 @ W2   (51200 x 64) @ (64 x 64); x1 lives in d_out (row stride 128)
// ---------------------------------------------------------------------------
__global__ __launch_bounds__(256) void gemm_h2(const float* __restrict__ x1,
                                               const float* __restrict__ W2,
                                               float* __restrict__ h2)
{
    __shared__ float xT[32][68];
    __shared__ float Wl[32][64];
    const int tid = threadIdx.x;
    const int tr = tid >> 4, tc = tid & 15;
    const int R0 = blockIdx.x * 64;
    float acc[4][4] = {{0.f,0.f,0.f,0.f},{0.f,0.f,0.f,0.f},
                       {0.f,0.f,0.f,0.f},{0.f,0.f,0.f,0.f}};
    for (int k0 = 0; k0 < 64; k0 += 32) {
        #pragma unroll
        for (int i = 0; i < 8; ++i) {
            int idx = tid + 256 * i;
            int kk = idx >> 6, c = idx & 63;
            Wl[kk][c] = W2[(k0 + kk) * 64 + c];
        }
        #pragma unroll
        for (int i = 0; i < 2; ++i) {
            int idx4 = tid + 256 * i;
            int row = idx4 >> 3, k4 = (idx4 & 7) << 2;
            const float4 v = *(const float4*)(x1 + (size_t)(R0 + row) * 128 + k0 + k4);
            xT[k4 + 0][row] = v.x; xT[k4 + 1][row] = v.y;
            xT[k4 + 2][row] = v.z; xT[k4 + 3][row] = v.w;
        }
        __syncthreads();
        #pragma unroll 8
        for (int k = 0; k < 32; ++k) {
            const float4 xv = *(const float4*)(&xT[k][tr << 2]);
            const float4 wv = *(const float4*)(&Wl[k][tc << 2]);
            const float xa[4] = {xv.x, xv.y, xv.z, xv.w};
            const float wa[4] = {wv.x, wv.y, wv.z, wv.w};
            #pragma unroll
            for (int i2 = 0; i2 < 4; ++i2)
                #pragma unroll
                for (int j2 = 0; j2 < 4; ++j2)
                    acc[i2][j2] += xa[i2] * wa[j2];
        }
        __syncthreads();
    }
    #pragma unroll
    for (int i2 = 0; i2 < 4; ++i2) {
        float4 o;
        o.x = acc[i2][0]; o.y = acc[i2][1]; o.z = acc[i2][2]; o.w = acc[i2][3];
        *(float4*)(h2 + (size_t)(R0 + tr * 4 + i2) * 64 + tc * 4) = o;
    }
}

// ---------------------------------------------------------------------------
// Attention kernel (one GAT attention + PV + elu).
// MODE 0 (layer 1): grid = 256*2, blockIdx = b*2 + head. F=32, all 200 rows.
//                   a = head ? aB : aA; h cols head*32..; out cols head*32..
// MODE 1 (layer 2): grid = 256*2, blockIdx = b*2 + half. F=64, 100 rows each.
//                   out cols 64..127.
// h staged TRANSPOSED in LDS: h_lds[f][j], pad 201 (conflict-free b32 access).
// Softmax: per-wave, 64 lanes cover j = lane + 64t (t=0..3), shfl_xor reduce.
// PV: lane = (f_ = lane&7, jh = lane>>3); each jh covers 25 j's; RB rows per
// pass share every h read; reduce over jh via shfl_xor(8,16,32).
// ---------------------------------------------------------------------------
template<int F, int RB, int MODE>
__global__ __launch_bounds__(256) void attn_kernel(const float* __restrict__ hmat,
                                                   const int* __restrict__ adj,
                                                   const float* __restrict__ aA,
                                                   const float* __restrict__ aB,
                                                   float* __restrict__ out)
{
    __shared__ float h_lds[F][201];
    __shared__ float p_lds[4][RB][N_NODES];
    __shared__ float src_lds[N_NODES];
    __shared__ float dst_lds[N_NODES];
    __shared__ float inv_lds[4][RB];

    const int tid = threadIdx.x;
    const int lane = tid & 63;
    const int w = tid >> 6;
    const int bx = blockIdx.x;
    const int b = bx >> 1, sub = bx & 1;

    int h_col0, out_col0, row0, nrows;
    const float* a;
    if (MODE == 0) {
        h_col0 = sub * 32; out_col0 = sub * 32; row0 = 0; nrows = N_NODES;
        a = sub ? aB : aA;
    } else {
        h_col0 = 0; out_col0 = 64; row0 = sub * (N_NODES / 2); nrows = N_NODES / 2;
        a = aA;
    }

    // stage h (transposed)
    const float* hb = hmat + (size_t)b * N_NODES * 64 + h_col0;
    for (int idx = tid; idx < N_NODES * F; idx += 256) {
        int j = idx / F, f = idx & (F - 1);
        h_lds[f][j] = hb[(size_t)j * 64 + f];
    }
    __syncthreads();

    // src/dst per node
    for (int i = tid; i < N_NODES; i += 256) {
        float s = 0.f, d2 = 0.f;
        #pragma unroll
        for (int f = 0; f < F; ++f) {
            float v = h_lds[f][i];
            s  += v * a[f];
            d2 += v * a[F + f];
        }
        src_lds[i] = s; dst_lds[i] = d2;
    }
    __syncthreads();

    float dv[4];
    #pragma unroll
    for (int t = 0; t < 4; ++t) {
        int j = lane + 64 * t;
        dv[t] = (j < N_NODES) ? dst_lds[j] : 0.f;
    }

    const int f_ = lane & 7, jh = lane >> 3;
    const int wr0 = row0 + w * (nrows >> 2);
    const int wr1 = wr0 + (nrows >> 2);

    for (int r0 = wr0; r0 < wr1; r0 += RB) {
        const int cnt = (RB < (wr1 - r0)) ? RB : (wr1 - r0);

        // ---- softmax rows r0..r0+cnt-1 (per-wave)
        for (int r = 0; r < cnt; ++r) {
            const int i = r0 + r;
            const float si = src_lds[i];
            float ev[4];
            #pragma unroll
            for (int t = 0; t < 4; ++t) {
                const int j = lane + 64 * t;
                float e = NEG_INF_V;
                if (j < N_NODES) {
                    float v = si + dv[t];
                    v = v > 0.f ? v : GAT_ALPHA * v;
                    e = (adj[i * N_NODES + j] > 0) ? v : NEG_INF_V;
                }
                ev[t] = e;
            }
            float m = fmaxf(fmaxf(ev[0], ev[1]), fmaxf(ev[2], ev[3]));
            #pragma unroll
            for (int s = 1; s < 64; s <<= 1) m = fmaxf(m, __shfl_xor(m, s, 64));
            float p[4], sum = 0.f;
            #pragma unroll
            for (int t = 0; t < 4; ++t) {
                const int j = lane + 64 * t;
                p[t] = (j < N_NODES) ? __expf(ev[t] - m) : 0.f;
                sum += p[t];
            }
            #pragma unroll
            for (int s = 1; s < 64; s <<= 1) sum += __shfl_xor(sum, s, 64);
            #pragma unroll
            for (int t = 0; t < 3; ++t) p_lds[w][r][lane + 64 * t] = p[t];
            if (lane < 8) p_lds[w][r][lane + 192] = p[3];
            if (lane == 0) inv_lds[w][r] = 1.0f / sum;
        }
        // p_lds / inv_lds are wave-private: no barrier needed.

        // ---- PV: acc[r][fb][q] = sum_j p[r][j] * h[fb*32+4f_+q][j]
        float acc[RB][F / 32][4];
        #pragma unroll
        for (int r = 0; r < RB; ++r)
            #pragma unroll
            for (int fb = 0; fb < F / 32; ++fb)
                #pragma unroll
                for (int q = 0; q < 4; ++q) acc[r][fb][q] = 0.f;

        for (int jj = 0; jj < 25; ++jj) {
            const int j = 25 * jh + jj;
            float pr[RB];
            #pragma unroll
            for (int r = 0; r < RB; ++r) pr[r] = p_lds[w][r][j];
            #pragma unroll
            for (int fb = 0; fb < F / 32; ++fb) {
                const int fbase = fb * 32 + 4 * f_;
                const float h0 = h_lds[fbase + 0][j];
                const float h1 = h_lds[fbase + 1][j];
                const float h2 = h_lds[fbase + 2][j];
                const float h3 = h_lds[fbase + 3][j];
                #pragma unroll
                for (int r = 0; r < RB; ++r) {
                    acc[r][fb][0] += pr[r] * h0;
                    acc[r][fb][1] += pr[r] * h1;
                    acc[r][fb][2] += pr[r] * h2;
                    acc[r][fb][3] += pr[r] * h3;
                }
            }
        }

        // reduce across jh (lane bits 3,4,5)
        #pragma unroll
        for (int r = 0; r < RB; ++r)
            #pragma unroll
            for (int fb = 0; fb < F / 32; ++fb)
                #pragma unroll
                for (int q = 0; q < 4; ++q) {
                    float v = acc[r][fb][q];
                    v += __shfl_xor(v, 8, 64);
                    v += __shfl_xor(v, 16, 64);
                    v += __shfl_xor(v, 32, 64);
                    acc[r][fb][q] = v;
                }

        if (lane < 8) {
            #pragma unroll
            for (int r = 0; r < RB; ++r) {
                if (r < cnt) {
                    const int i = r0 + r;
                    const float inv = inv_lds[w][r];
                    #pragma unroll
                    for (int fb = 0; fb < F / 32; ++fb) {
                        float vv[4];
                        #pragma unroll
                        for (int q = 0; q < 4; ++q) {
                            float v2 = acc[r][fb][q] * inv;
                            vv[q] = v2 > 0.f ? v2 : expm1f(v2);
                        }
                        float4 o;
                        o.x = vv[0]; o.y = vv[1]; o.z = vv[2]; o.w = vv[3];
                        *(float4*)(out + (size_t)(b * N_NODES + i) * 128
                                   + out_col0 + fb * 32 + 4 * f_) = o;
                    }
                }
            }
        }
    }
}

extern "C" void kernel_launch(void* const* d_in, const int* in_sizes, int n_in,
                              void* d_out, int out_size, void* d_ws, size_t ws_size,
                              hipStream_t stream)
{
    const float* x   = (const float*)d_in[0];
    const int*   adj = (const int*)  d_in[1];
    const float* W10 = (const float*)d_in[2];
    const float* a10 = (const float*)d_in[3];
    const float* W11 = (const float*)d_in[4];
    const float* a11 = (const float*)d_in[5];
    const float* W2  = (const float*)d_in[6];
    const float* a2  = (const float*)d_in[7];
    float* out = (float*)d_out;
    float* h   = (float*)d_ws;   // 51200*64 f32 = 13.1 MB, reused for h1 then h2

    // layer 1: h1 = x @ [W10|W11]
    gemm_h1<<<800, 256, 0, stream>>>(x, W10, W11, h);
    // layer 1 attention (both heads) -> out cols 0..63
    attn_kernel<32, 5, 0><<<512, 256, 0, stream>>>(h, adj, a10, a11, out);
    // layer 2: h2 = x1 @ W2  (x1 = out cols 0..63)
    gemm_h2<<<800, 256, 0, stream>>>(out, W2, h);
    // layer 2 attention -> out cols 64..127
    attn_kernel<64, 3, 1><<<512, 256, 0, stream>>>(h, adj, a2, a2, out);
}

// Round 2
// 136.041 us; speedup vs baseline: 1.6362x; 1.6362x over previous
//
#include <hip/hip_runtime.h>
#include <cmath>

typedef __attribute__((ext_vector_type(8))) short short8;
typedef __attribute__((ext_vector_type(4))) float f32x4;

#define ALPHA_ 0.2f
#define NEGINF (-9.0e15f)

__device__ __forceinline__ ushort f2b(float f) {
    union { float f; unsigned u; } v; v.f = f;
    unsigned r = v.u + 0x7fffu + ((v.u >> 16) & 1u);
    return (ushort)(r >> 16);
}

// ---------------------------------------------------------------------------
// prep: W -> transposed bf16 tables. WT1 = [64 n][320 k] (n: 0..31 from W10,
// 32..63 from W11), WT2 = [64 n][64 k].
// ---------------------------------------------------------------------------
__global__ __launch_bounds__(256) void prep_kernel(const float* __restrict__ W10,
                                                   const float* __restrict__ W11,
                                                   const float* __restrict__ W2,
                                                   ushort* __restrict__ WT1,
                                                   ushort* __restrict__ WT2)
{
    const int tid = threadIdx.x;
    for (int idx = tid; idx < 64 * 320; idx += 256) {
        int n = idx / 320, k = idx % 320;
        float v = (n < 32) ? W10[k * 32 + n] : W11[k * 32 + (n - 32)];
        WT1[idx] = f2b(v);
    }
    for (int idx = tid; idx < 64 * 64; idx += 256) {
        int n = idx / 64, k = idx % 64;
        WT2[idx] = f2b(W2[k * 64 + n]);
    }
}

// ---------------------------------------------------------------------------
// gemm: H[51200 x 64] = X[51200 x K (row stride LDX)] @ W[K x 64]
// bf16 MFMA 16x16x32. A-fragments loaded straight from global f32 (8
// consecutive k per lane -> two float4, 128B/row segments) and converted
// in-register. W^T bf16 staged once per block into padded LDS.
// Block = 256 thr = 4 waves, each wave owns a 16-row m-tile; 64 rows/block.
// ---------------------------------------------------------------------------
template<int K, int LDX>
__global__ __launch_bounds__(256) void gemm_mfma(const float* __restrict__ X,
                                                 const ushort* __restrict__ WT,
                                                 float* __restrict__ H)
{
    constexpr int KP = K + 8;                    // pad: stride/4 mod 32 = 4 -> 2-way banks (free)
    __shared__ ushort wt_lds[64][KP];
    const int tid = threadIdx.x;
    constexpr int CH = 64 * (K / 8);
    for (int c = tid; c < CH; c += 256) {
        int n = c / (K / 8), kc = (c % (K / 8)) * 8;
        *(short8*)&wt_lds[n][kc] = *(const short8*)&WT[n * K + kc];
    }
    __syncthreads();

    const int lane = tid & 63, w = tid >> 6;
    const int m = lane & 15;                     // A row within tile
    const int ko = (lane >> 4) * 8;              // k sub-offset of this lane's fragment
    const size_t row = (size_t)blockIdx.x * 64 + w * 16 + m;

    f32x4 acc[4] = {{0,0,0,0},{0,0,0,0},{0,0,0,0},{0,0,0,0}};
    #pragma unroll
    for (int k0 = 0; k0 < K; k0 += 32) {
        const float4 x0 = *(const float4*)&X[row * LDX + k0 + ko];
        const float4 x1 = *(const float4*)&X[row * LDX + k0 + ko + 4];
        short8 a;
        a[0] = (short)f2b(x0.x); a[1] = (short)f2b(x0.y);
        a[2] = (short)f2b(x0.z); a[3] = (short)f2b(x0.w);
        a[4] = (short)f2b(x1.x); a[5] = (short)f2b(x1.y);
        a[6] = (short)f2b(x1.z); a[7] = (short)f2b(x1.w);
        #pragma unroll
        for (int nt = 0; nt < 4; ++nt) {
            const short8 bfr = *(const short8*)&wt_lds[nt * 16 + m][k0 + ko];
            acc[nt] = __builtin_amdgcn_mfma_f32_16x16x32_bf16(a, bfr, acc[nt], 0, 0, 0);
        }
    }

    const size_t rbase = (size_t)blockIdx.x * 64 + w * 16 + (lane >> 4) * 4;
    #pragma unroll
    for (int nt = 0; nt < 4; ++nt)
        #pragma unroll
        for (int r = 0; r < 4; ++r)
            H[(rbase + r) * 64 + nt * 16 + m] = acc[nt][r];
}

// ---------------------------------------------------------------------------
// Fused GAT attention, MFMA PV.
// MODE 0: grid 256*2*2, bx = ((b*2+head)*2+sub). F=32, out cols head*32..
// MODE 1: grid 256*2,   bx = b*2+sub.            F=64, out cols 64..127
// sub splits the 13 m-tiles (16 rows each, 200 rows + 8-row tail) 7/6.
// hT: bf16 [F][232] (224 = 7*32 MFMA K, j>=200 zero).  Wave-private P tile
// pT[w]: bf16 [16 rows][232].  Softmax: 4 rows/wave concurrent, 16 lanes/row,
// 2 packed j per lane, 4-stage shfl reduce.  PV: 7 k-steps of 16x16x32.
// ---------------------------------------------------------------------------
template<int F, int MODE>
__global__ __launch_bounds__(256) void attn_mfma(const float* __restrict__ hmat,
                                                 const int* __restrict__ adj,
                                                 const float* __restrict__ aA,
                                                 const float* __restrict__ aB,
                                                 float* __restrict__ out)
{
    __shared__ ushort hT[F][232];
    __shared__ ushort pT[4][16][232];
    __shared__ float src_lds[200], dst_lds[200];
    __shared__ float inv_lds[4][16];

    const int tid = threadIdx.x;
    const int lane = tid & 63, w = tid >> 6;
    const int bx = blockIdx.x;
    int b, sub, h_col0, out_col0;
    const float* a;
    if (MODE == 0) {
        b = bx >> 2; const int head = (bx >> 1) & 1; sub = bx & 1;
        h_col0 = head * 32; out_col0 = head * 32;
        a = head ? aB : aA;
    } else {
        b = bx >> 1; sub = bx & 1;
        h_col0 = 0; out_col0 = 64;
        a = aA;
    }
    const float* hb = hmat + (size_t)b * 200 * 64 + h_col0;

    // stage h^T bf16 (zero-pad j in [200,224))
    for (int idx = tid; idx < F * 224; idx += 256) {
        const int f = idx % F, j = idx / F;
        const float v = (j < 200) ? hb[(size_t)j * 64 + f] : 0.f;
        hT[f][j] = f2b(v);
    }
    // per-node src/dst dots (f32)
    for (int i = tid; i < 200; i += 256) {
        float s = 0.f, d = 0.f;
        #pragma unroll
        for (int f = 0; f < F; ++f) {
            const float v = hb[(size_t)i * 64 + f];
            s += v * a[f];
            d += v * a[F + f];
        }
        src_lds[i] = s; dst_lds[i] = d;
    }
    __syncthreads();

    const int m = lane & 15;      // 16-lane group position
    const int g = lane >> 4;      // group id 0..3
    const int t0 = sub ? 7 : 0, t1 = sub ? 13 : 7;

    for (int t = t0 + w; t < t1; t += 4) {
        const int i0 = t * 16;

        // ---- softmax: 16 rows, 4 at a time (one per 16-lane group)
        for (int rr = 0; rr < 4; ++rr) {
            const int r = rr * 4 + g;
            const int i = i0 + r;
            const bool valid = (i < 200);
            const float si = valid ? src_lds[i] : 0.f;
            float ev[14];
            float mx = NEGINF;
            #pragma unroll
            for (int jj = 0; jj < 7; ++jj) {
                const int j = 2 * m + 32 * jj;
                float e0 = NEGINF, e1 = NEGINF;
                if (valid && j < 200) {
                    const int2 ad = *(const int2*)&adj[i * 200 + j];
                    float v0 = si + dst_lds[j];
                    float v1 = si + dst_lds[j + 1];
                    v0 = fmaxf(v0, ALPHA_ * v0);          // leaky-relu (alpha<1)
                    v1 = fmaxf(v1, ALPHA_ * v1);
                    e0 = (ad.x > 0) ? v0 : NEGINF;
                    e1 = (ad.y > 0) ? v1 : NEGINF;
                }
                ev[2 * jj] = e0; ev[2 * jj + 1] = e1;
                mx = fmaxf(mx, fmaxf(e0, e1));
            }
            #pragma unroll
            for (int s = 1; s < 16; s <<= 1) mx = fmaxf(mx, __shfl_xor(mx, s, 64));
            float sum = 0.f;
            #pragma unroll
            for (int jj = 0; jj < 7; ++jj) {
                const float p0 = __expf(ev[2 * jj]     - mx);
                const float p1 = __expf(ev[2 * jj + 1] - mx);
                sum += p0 + p1;
                const unsigned pk = (unsigned)f2b(p0) | ((unsigned)f2b(p1) << 16);
                *(unsigned*)&pT[w][r][2 * m + 32 * jj] = pk;
            }
            #pragma unroll
            for (int s = 1; s < 16; s <<= 1) sum += __shfl_xor(sum, s, 64);
            if (m == 0) inv_lds[w][r] = 1.f / sum;
        }

        // ---- PV via MFMA: D[16 x F] = P[16 x 224] @ hT^T[224 x F]
        #pragma unroll
        for (int nt = 0; nt < F / 16; ++nt) {
            f32x4 acc = {0, 0, 0, 0};
            #pragma unroll
            for (int ks = 0; ks < 7; ++ks) {
                const short8 af = *(const short8*)&pT[w][m][ks * 32 + g * 8];
                const short8 bf = *(const short8*)&hT[nt * 16 + m][ks * 32 + g * 8];
                acc = __builtin_amdgcn_mfma_f32_16x16x32_bf16(af, bf, acc, 0, 0, 0);
            }
            const int col = out_col0 + nt * 16 + m;
            #pragma unroll
            for (int r2 = 0; r2 < 4; ++r2) {
                const int row = g * 4 + r2;
                const int i = i0 + row;
                if (i < 200) {
                    float v = acc[r2] * inv_lds[w][row];
                    v = (v > 0.f) ? v : expm1f(v);        // elu
                    out[((size_t)b * 200 + i) * 128 + col] = v;
                }
            }
        }
    }
}

extern "C" void kernel_launch(void* const* d_in, const int* in_sizes, int n_in,
                              void* d_out, int out_size, void* d_ws, size_t ws_size,
                              hipStream_t stream)
{
    const float* x   = (const float*)d_in[0];
    const int*   adj = (const int*)  d_in[1];
    const float* W10 = (const float*)d_in[2];
    const float* a10 = (const float*)d_in[3];
    const float* W11 = (const float*)d_in[4];
    const float* a11 = (const float*)d_in[5];
    const float* W2  = (const float*)d_in[6];
    const float* a2  = (const float*)d_in[7];
    float* out = (float*)d_out;

    float*  h   = (float*)d_ws;                               // 51200*64 f32 = 13.1 MB
    ushort* WT1 = (ushort*)((char*)d_ws + (size_t)51200 * 64 * 4);
    ushort* WT2 = WT1 + 64 * 320;

    prep_kernel<<<1, 256, 0, stream>>>(W10, W11, W2, WT1, WT2);
    gemm_mfma<320, 320><<<800, 256, 0, stream>>>(x, WT1, h);
    attn_mfma<32, 0><<<1024, 256, 0, stream>>>(h, adj, a10, a11, out);
    gemm_mfma<64, 128><<<800, 256, 0, stream>>>(out, WT2, h);
    attn_mfma<64, 1><<<512, 256, 0, stream>>>(h, adj, a2, a2, out);
}

// Round 4
// 129.826 us; speedup vs baseline: 1.7145x; 1.0479x over previous
//
#include <hip/hip_runtime.h>
#include <cmath>

typedef __attribute__((ext_vector_type(8))) short short8;
typedef __attribute__((ext_vector_type(4))) float f32x4;

#define ALPHA_ 0.2f
#define NEGINF (-9.0e15f)

__device__ __forceinline__ ushort f2b(float f) {
    union { float f; unsigned u; } v; v.f = f;
    unsigned r = v.u + 0x7fffu + ((v.u >> 16) & 1u);
    return (ushort)(r >> 16);
}

// ---------------------------------------------------------------------------
// prep (grid 200 x 256):
//  - adjb[i][0..7]: bitmask of adj row i (bit j%32 of dword j/32), j>=200 -> 0
//  - WT1[64][320], WT2[64][64]: transposed bf16 weights
//  - wv1[4][320] = {W10@a10_src, W10@a10_dst, W11@a11_src, W11@a11_dst} (f32)
//  - wv2[2][64]  = {W2@a2_src, W2@a2_dst} (f32)
//  - HT pad columns [200,224) zeroed for all 256*64 feature rows
// ---------------------------------------------------------------------------
__global__ __launch_bounds__(256) void prep_kernel(
    const int* __restrict__ adj, const float* __restrict__ W10,
    const float* __restrict__ W11, const float* __restrict__ W2,
    const float* __restrict__ a10, const float* __restrict__ a11,
    const float* __restrict__ a2,
    unsigned* __restrict__ adjb, ushort* __restrict__ WT1,
    ushort* __restrict__ WT2, float* __restrict__ wv1,
    float* __restrict__ wv2, ushort* __restrict__ HT)
{
    const int bx = blockIdx.x, tid = threadIdx.x;
    if (tid < 8) {
        unsigned mask = 0;
        for (int u = 0; u < 32; ++u) {
            const int j = tid * 32 + u;
            if (j < 200 && adj[bx * 200 + j] > 0) mask |= (1u << u);
        }
        adjb[bx * 8 + tid] = mask;
    }
    const int gidx = bx * 256 + tid;                 // 0..51199
    if (gidx < 64 * 320) {
        const int n = gidx / 320, k = gidx % 320;
        WT1[gidx] = f2b(n < 32 ? W10[k * 32 + n] : W11[k * 32 + (n - 32)]);
    }
    if (gidx < 64 * 64) {
        const int n = gidx >> 6, k = gidx & 63;
        WT2[gidx] = f2b(W2[k * 64 + n]);
    }
    if (gidx < 1280) {                               // wv1
        const int k = gidx >> 2, q = gidx & 3;
        const float* Wp = (q < 2) ? (W10 + k * 32) : (W11 + k * 32);
        const float* av = ((q < 2) ? a10 : a11) + (q & 1) * 32;
        float s = 0.f;
        for (int f = 0; f < 32; ++f) s += Wp[f] * av[f];
        wv1[q * 320 + k] = s;
    }
    if (gidx < 128) {                                // wv2
        const int k = gidx >> 1, q = gidx & 1;
        float s = 0.f;
        for (int f = 0; f < 64; ++f) s += W2[k * 64 + f] * a2[q * 64 + f];
        wv2[q * 64 + k] = s;
    }
    if (gidx < 256 * 64 * 3) {                       // HT pad zero (3 x uint4 per row)
        const int c = gidx % 3, bf = gidx / 3;
        uint4 z{0, 0, 0, 0};
        *(uint4*)&HT[(size_t)bf * 224 + 200 + c * 8] = z;
    }
}

// ---------------------------------------------------------------------------
// sd1: per global row i, sd1[i][4] = {src_h0, dst_h0, src_h1, dst_h1}
//      = dot(x[i, 0:320], wv1[q]).  One wave per row (4 rows/block).
// ---------------------------------------------------------------------------
__global__ __launch_bounds__(256) void sd1_kernel(const float* __restrict__ x,
                                                  const float* __restrict__ wv1,
                                                  float* __restrict__ sd1)
{
    __shared__ __attribute__((aligned(16))) float wl[4 * 320];
    const int tid = threadIdx.x;
    for (int i = tid; i < 1280; i += 256) wl[i] = wv1[i];
    __syncthreads();
    const int lane = tid & 63, w = tid >> 6;
    const size_t row = (size_t)blockIdx.x * 4 + w;
    float a0 = 0.f, a1 = 0.f, a2v = 0.f, a3 = 0.f;
    #pragma unroll
    for (int c = 0; c < 5; ++c) {
        const float xv = x[row * 320 + c * 64 + lane];
        const int k = c * 64 + lane;
        a0 += xv * wl[k]; a1 += xv * wl[320 + k];
        a2v += xv * wl[640 + k]; a3 += xv * wl[960 + k];
    }
    #pragma unroll
    for (int s = 1; s < 64; s <<= 1) {
        a0 += __shfl_xor(a0, s, 64); a1 += __shfl_xor(a1, s, 64);
        a2v += __shfl_xor(a2v, s, 64); a3 += __shfl_xor(a3, s, 64);
    }
    if (lane == 0) {
        float4 o; o.x = a0; o.y = a1; o.z = a2v; o.w = a3;
        *(float4*)&sd1[row * 4] = o;
    }
}

// sd2: sd2[i][2] = dot(x1[i, 0:64], wv2[q]); x1 = out cols 0..63 (stride 128)
__global__ __launch_bounds__(256) void sd2_kernel(const float* __restrict__ x1,
                                                  const float* __restrict__ wv2,
                                                  float* __restrict__ sd2)
{
    __shared__ __attribute__((aligned(16))) float wl[128];
    const int tid = threadIdx.x;
    if (tid < 128) wl[tid] = wv2[tid];
    __syncthreads();
    const int lane = tid & 63, w = tid >> 6;
    const size_t row = (size_t)blockIdx.x * 4 + w;
    const float v = x1[row * 128 + lane];
    float a0 = v * wl[lane], a1 = v * wl[64 + lane];
    #pragma unroll
    for (int s = 1; s < 64; s <<= 1) {
        a0 += __shfl_xor(a0, s, 64); a1 += __shfl_xor(a1, s, 64);
    }
    if (lane == 0) {
        float2 o; o.x = a0; o.y = a1;
        *(float2*)&sd2[row * 2] = o;
    }
}

// ---------------------------------------------------------------------------
// gemm: HT[b][f][jpad224] (bf16) = X[51200 x K] @ W[K x 64]
// ---------------------------------------------------------------------------
template<int K, int LDX>
__global__ __launch_bounds__(256) void gemm_mfma(const float* __restrict__ X,
                                                 const ushort* __restrict__ WT,
                                                 ushort* __restrict__ HT)
{
    constexpr int KP = K + 8;
    __shared__ __attribute__((aligned(16))) ushort wt_lds[64][KP];
    const int tid = threadIdx.x;
    constexpr int CH = 64 * (K / 8);
    for (int c = tid; c < CH; c += 256) {
        int n = c / (K / 8), kc = (c % (K / 8)) * 8;
        *(short8*)&wt_lds[n][kc] = *(const short8*)&WT[n * K + kc];
    }
    __syncthreads();

    const int lane = tid & 63, w = tid >> 6;
    const int m = lane & 15, g = lane >> 4;
    const int ko = g * 8;
    const size_t row = (size_t)blockIdx.x * 64 + w * 16 + m;

    f32x4 acc[4] = {{0,0,0,0},{0,0,0,0},{0,0,0,0},{0,0,0,0}};
    #pragma unroll
    for (int k0 = 0; k0 < K; k0 += 32) {
        const float4 x0 = *(const float4*)&X[row * LDX + k0 + ko];
        const float4 x1 = *(const float4*)&X[row * LDX + k0 + ko + 4];
        short8 a;
        a[0] = (short)f2b(x0.x); a[1] = (short)f2b(x0.y);
        a[2] = (short)f2b(x0.z); a[3] = (short)f2b(x0.w);
        a[4] = (short)f2b(x1.x); a[5] = (short)f2b(x1.y);
        a[6] = (short)f2b(x1.z); a[7] = (short)f2b(x1.w);
        #pragma unroll
        for (int nt = 0; nt < 4; ++nt) {
            const short8 bfr = *(const short8*)&wt_lds[nt * 16 + m][k0 + ko];
            acc[nt] = __builtin_amdgcn_mfma_f32_16x16x32_bf16(a, bfr, acc[nt], 0, 0, 0);
        }
    }

    const unsigned rb = (unsigned)blockIdx.x * 64 + w * 16 + g * 4;  // 4 | 200
    const unsigned bt = rb / 200u;
    const unsigned ir = rb - bt * 200u;
    #pragma unroll
    for (int nt = 0; nt < 4; ++nt) {
        uint2 pk;
        pk.x = (unsigned)f2b(acc[nt][0]) | ((unsigned)f2b(acc[nt][1]) << 16);
        pk.y = (unsigned)f2b(acc[nt][2]) | ((unsigned)f2b(acc[nt][3]) << 16);
        *(uint2*)&HT[((size_t)bt * 64 + nt * 16 + m) * 224 + ir] = pk;
    }
}

// ---------------------------------------------------------------------------
// Fused GAT attention. Lane (m, g) owns softmax row i0+m, j-slice
// {ks*32 + g*8 + u}.  Row reduce = 2 shfl_xor.  P built as bf16 MFMA
// A-fragments in registers (pure-C f2b).  exp arg clamped <= 0 -> p <= 1.
// MODE 0: bx = ((b*2+head)*2+sub), F=32, sd = sd1[row][4], out cols head*32..
// MODE 1: bx = b*2+sub,            F=64, sd = sd2[row][2], out cols 64..127
// ---------------------------------------------------------------------------
template<int F, int MODE>
__global__ __launch_bounds__(256) void attn_mfma(const ushort* __restrict__ HT,
                                                 const unsigned* __restrict__ adjb,
                                                 const float* __restrict__ sd,
                                                 float* __restrict__ out)
{
    __shared__ __attribute__((aligned(16))) ushort hT[F][232];
    __shared__ __attribute__((aligned(16))) float src_l[224];
    __shared__ __attribute__((aligned(16))) float dst_l[224];
    __shared__ __attribute__((aligned(16))) unsigned adjl[208][8];
    __shared__ float inv_l[4][16];

    const int tid = threadIdx.x;
    const int lane = tid & 63, w = tid >> 6;
    const int bx = blockIdx.x;
    int b, sub, hoff, outc0, head;
    if (MODE == 0) {
        b = bx >> 2; head = (bx >> 1) & 1; sub = bx & 1;
        hoff = head * 32; outc0 = head * 32;
    } else {
        b = bx >> 1; head = 0; sub = bx & 1;
        hoff = 0; outc0 = 64;
    }

    // stage hT (coalesced short8)
    const ushort* hg = HT + ((size_t)b * 64 + hoff) * 224;
    for (int idx = tid; idx < F * 28; idx += 256) {
        const int f = idx / 28, c = idx % 28;
        *(short8*)&hT[f][c * 8] = *(const short8*)&hg[(size_t)f * 224 + c * 8];
    }
    // stage adj bitmasks (rows 200..207 zero)
    for (int idx = tid; idx < 208 * 8; idx += 256) {
        const int i = idx >> 3, c = idx & 7;
        adjl[i][c] = (i < 200) ? adjb[i * 8 + c] : 0u;
    }
    // stage src/dst (f32-exact from sd tables)
    if (tid < 224) {
        float s = 0.f, d = 0.f;
        if (tid < 200) {
            if (MODE == 0) {
                const float4 q4 = *(const float4*)&sd[(size_t)(b * 200 + tid) * 4];
                s = head ? q4.z : q4.x;
                d = head ? q4.w : q4.y;
            } else {
                const float2 q2 = *(const float2*)&sd[(size_t)(b * 200 + tid) * 2];
                s = q2.x; d = q2.y;
            }
        }
        src_l[tid] = s; dst_l[tid] = d;
    }
    __syncthreads();

    const int m = lane & 15, g = lane >> 4;
    const int t0 = sub ? 7 : 0, t1 = sub ? 13 : 7;

    for (int t = t0 + w; t < t1; t += 4) {
        const int i0 = t * 16;
        const int isf = i0 + m;
        const float si = src_l[isf];

        unsigned bitsv[7];
        float mx = NEGINF;
        #pragma unroll
        for (int ks = 0; ks < 7; ++ks) {
            bitsv[ks] = (adjl[isf][ks] >> (g * 8)) & 0xffu;
            const float4 d0 = *(const float4*)&dst_l[ks * 32 + g * 8];
            const float4 d1 = *(const float4*)&dst_l[ks * 32 + g * 8 + 4];
            const float dvv[8] = {d0.x, d0.y, d0.z, d0.w, d1.x, d1.y, d1.z, d1.w};
            #pragma unroll
            for (int u = 0; u < 8; ++u) {
                float v = si + dvv[u];
                v = fmaxf(v, ALPHA_ * v);
                const float e = ((bitsv[ks] >> u) & 1u) ? v : NEGINF;
                mx = fmaxf(mx, e);
            }
        }
        mx = fmaxf(mx, __shfl_xor(mx, 16, 64));
        mx = fmaxf(mx, __shfl_xor(mx, 32, 64));

        float sum = 0.f;
        short8 af[7];
        #pragma unroll
        for (int ks = 0; ks < 7; ++ks) {
            const float4 d0 = *(const float4*)&dst_l[ks * 32 + g * 8];
            const float4 d1 = *(const float4*)&dst_l[ks * 32 + g * 8 + 4];
            const float dvv[8] = {d0.x, d0.y, d0.z, d0.w, d1.x, d1.y, d1.z, d1.w};
            #pragma unroll
            for (int u = 0; u < 8; ++u) {
                float v = si + dvv[u];
                v = fmaxf(v, ALPHA_ * v);
                const float e = ((bitsv[ks] >> u) & 1u) ? v : NEGINF;
                const float p = __expf(fminf(e - mx, 0.f));   // p <= 1 guaranteed
                sum += p;
                af[ks][u] = (short)f2b(p);
            }
        }
        sum += __shfl_xor(sum, 16, 64);
        sum += __shfl_xor(sum, 32, 64);
        if (g == 0) inv_l[w][m] = 1.f / sum;

        #pragma unroll
        for (int nt = 0; nt < F / 16; ++nt) {
            f32x4 acc = {0, 0, 0, 0};
            #pragma unroll
            for (int ks = 0; ks < 7; ++ks) {
                const short8 bf = *(const short8*)&hT[nt * 16 + m][ks * 32 + g * 8];
                acc = __builtin_amdgcn_mfma_f32_16x16x32_bf16(af[ks], bf, acc, 0, 0, 0);
            }
            #pragma unroll
            for (int r = 0; r < 4; ++r) {
                const int row = g * 4 + r;
                const int ii = i0 + row;
                if (ii < 200) {
                    float vv = acc[r] * inv_l[w][row];
                    vv = (vv > 0.f) ? vv : expm1f(vv);
                    out[((size_t)b * 200 + ii) * 128 + outc0 + nt * 16 + m] = vv;
                }
            }
        }
    }
}

extern "C" void kernel_launch(void* const* d_in, const int* in_sizes, int n_in,
                              void* d_out, int out_size, void* d_ws, size_t ws_size,
                              hipStream_t stream)
{
    const float* x   = (const float*)d_in[0];
    const int*   adj = (const int*)  d_in[1];
    const float* W10 = (const float*)d_in[2];
    const float* a10 = (const float*)d_in[3];
    const float* W11 = (const float*)d_in[4];
    const float* a11 = (const float*)d_in[5];
    const float* W2  = (const float*)d_in[6];
    const float* a2  = (const float*)d_in[7];
    float* out = (float*)d_out;

    char* ws = (char*)d_ws;
    ushort*   HT   = (ushort*)  ws;                  // 7,340,032 B
    ushort*   WT1  = (ushort*) (ws + 7340032);       //    40,960 B
    ushort*   WT2  = (ushort*) (ws + 7380992);       //     8,192 B
    unsigned* adjb = (unsigned*)(ws + 7389184);      //     6,400 B
    float*    wv1  = (float*)  (ws + 7395584);       //     5,120 B
    float*    wv2  = (float*)  (ws + 7400704);       //       512 B
    float*    sd1  = (float*)  (ws + 7401216);       //   819,200 B
    float*    sd2  = (float*)  (ws + 8220416);       //   409,600 B  (total 8.63 MB)

    prep_kernel<<<200, 256, 0, stream>>>(adj, W10, W11, W2, a10, a11, a2,
                                         adjb, WT1, WT2, wv1, wv2, HT);
    sd1_kernel<<<12800, 256, 0, stream>>>(x, wv1, sd1);
    gemm_mfma<320, 320><<<800, 256, 0, stream>>>(x, WT1, HT);
    attn_mfma<32, 0><<<1024, 256, 0, stream>>>(HT, adjb, sd1, out);
    sd2_kernel<<<12800, 256, 0, stream>>>(out, wv2, sd2);
    gemm_mfma<64, 128><<<800, 256, 0, stream>>>(out, WT2, HT);
    attn_mfma<64, 1><<<512, 256, 0, stream>>>(HT, adjb, sd2, out);
}